// Round 5
// baseline (228.177 us; speedup 1.0000x reference)
//
#include <hip/hip_runtime.h>

#define N2   8192
#define DDIM 256
#define NTRI 528  // 32*33/2 upper-triangle 256x256 blocks

static constexpr float INV_T = 1.0f / 0.07f;

using bf16x8 = __attribute__((ext_vector_type(8))) __bf16;
using f32x4  = __attribute__((ext_vector_type(4))) float;
using u16x4  = __attribute__((ext_vector_type(4))) unsigned short;
typedef unsigned short u16;
typedef unsigned int   u32;

#define GL2LDS(gp, lp) __builtin_amdgcn_global_load_lds( \
    (const __attribute__((address_space(1))) void*)(gp), \
    (__attribute__((address_space(3))) void*)(lp), 16, 0, 0)

// ---------- helpers ----------
__device__ __forceinline__ u16 f2bf(float f) {
    u32 u = __float_as_uint(f);
    u32 r = (u + 0x7fffu + ((u >> 16) & 1u)) >> 16;   // RNE
    return (u16)r;
}

// ---------- kernel 1: normalize rows, f32 -> bf16 ----------
__global__ void ntx_norm(const float* __restrict__ z1, const float* __restrict__ z2,
                         u16* __restrict__ zn)
{
    const int w    = threadIdx.x >> 6;
    const int lane = threadIdx.x & 63;
    const int row  = blockIdx.x * 4 + w;

    const float* src = (row < 4096) ? (z1 + (size_t)row * DDIM)
                                    : (z2 + (size_t)(row - 4096) * DDIM);
    float4 v = *(const float4*)(src + lane * 4);
    float ss = v.x * v.x + v.y * v.y + v.z * v.z + v.w * v.w;
    #pragma unroll
    for (int m = 1; m < 64; m <<= 1) ss += __shfl_xor(ss, m, 64);

    float inv = 1.0f / fmaxf(sqrtf(ss), 1e-8f);

    u16x4 o;
    o.x = f2bf(v.x * inv); o.y = f2bf(v.y * inv);
    o.z = f2bf(v.z * inv); o.w = f2bf(v.w * inv);
    *(u16x4*)(zn + (size_t)row * DDIM + lane * 4) = o;
}

// ---------- kernel 2: 256x256 upper-triangle sim blocks ----------
// 8 waves (2 row x 4 col), wave tile 128x64, BK=64, SINGLE-buffered LDS (64 KB
// -> 2 blocks/CU for cross-block latency hiding + 528/512 = 1.03 round packing),
// global_load_lds staging: linear LDS dest + inverse-swizzled global source,
// XOR-swizzled ds_read (rule 21 pair). Simple full-drain sync (R2-proven).
__global__ __launch_bounds__(512, 4)
void ntx_gemm(const u16* __restrict__ zn, float* __restrict__ rowp,
              float* __restrict__ colp, float* __restrict__ pos)
{
    __shared__ u16 lsA[16384];   // 256 rows x 64 bf16 (128 B/row)
    __shared__ u16 lsB[16384];

    const int tid  = threadIdx.x;
    const int lane = tid & 63;
    const int w    = tid >> 6;       // 0..7
    const int wr   = w >> 2;         // 0..1  (row half)
    const int wc   = w & 3;          // 0..3  (col quarter)

    // triangle decode: blockIdx.x -> (br, bc), br <= bc
    const int t = (int)blockIdx.x;
    int br = (int)((65.0f - sqrtf(4225.0f - 8.0f * (float)t)) * 0.5f);
    while ((br + 1) * (65 - (br + 1)) / 2 <= t) ++br;
    while (br * (65 - br) / 2 > t) --br;
    const int bc = br + (t - br * (65 - br) / 2);

    const int fr  = lane & 15;               // fragment row/col
    const int kl  = lane >> 4;               // k-group 0..3
    const int swz = (fr & 7) << 4;           // read-side swizzle

    // staging: issue i covers rows i*64 + w*8 + (lane>>3); linear LDS dest,
    // inverse-swizzled global source column
    const int srow = w * 8 + (lane >> 3);
    const int scsw = ((lane & 7) * 16) ^ ((lane >> 3) << 4);

    auto stage = [&](int kt) {
        const char* gA = (const char*)zn + (size_t)(br * 256 + srow) * 512 + kt * 128 + scsw;
        const char* gB = (const char*)zn + (size_t)(bc * 256 + srow) * 512 + kt * 128 + scsw;
        u16* lA = &lsA[w * 512];
        u16* lB = &lsB[w * 512];
        #pragma unroll
        for (int i = 0; i < 4; ++i) {
            GL2LDS(gA + (size_t)i * 32768, lA + i * 4096);
            GL2LDS(gB + (size_t)i * 32768, lB + i * 4096);
        }
    };

    f32x4 acc[8][4] = {};

    stage(0);
    __syncthreads();                 // staged data visible (vmcnt+lgkm drain)

    #pragma unroll
    for (int kt = 0; kt < 4; ++kt) {
        #pragma unroll
        for (int ks = 0; ks < 2; ++ks) {
            const int kb = ks * 64 + kl * 16;
            bf16x8 af[8], bv[4];
            #pragma unroll
            for (int mf = 0; mf < 8; ++mf) {
                const int r = wr * 128 + mf * 16 + fr;
                af[mf] = *(const bf16x8*)((const char*)lsA + r * 128 + (kb ^ swz));
            }
            #pragma unroll
            for (int nf = 0; nf < 4; ++nf) {
                const int c = wc * 64 + nf * 16 + fr;
                bv[nf] = *(const bf16x8*)((const char*)lsB + c * 128 + (kb ^ swz));
            }
            #pragma unroll
            for (int mf = 0; mf < 8; ++mf)
                #pragma unroll
                for (int nf = 0; nf < 4; ++nf)
                    acc[mf][nf] = __builtin_amdgcn_mfma_f32_16x16x32_bf16(
                        af[mf], bv[nf], acc[mf][nf], 0, 0, 0);
        }
        if (kt < 3) {
            __syncthreads();         // all waves done reading LDS
            stage(kt + 1);
            __syncthreads();         // staged data visible
        }
    }

    // ---- epilogue: e = exp((dot-1)/T), diag masked ----
    // row sums -> rowp[row][bc*4+wc]; col sums -> colp[col][br*2+wr] (offdiag)
    const bool diag   = (br == bc);
    const bool posblk = (bc == br + 16);
    float colsum[4] = {0.f, 0.f, 0.f, 0.f};

    #pragma unroll
    for (int mf = 0; mf < 8; ++mf) {
        float rs[4] = {0.f, 0.f, 0.f, 0.f};
        const int rloc0 = wr * 128 + mf * 16 + kl * 4;      // local rows rloc0..rloc0+3
        #pragma unroll
        for (int nf = 0; nf < 4; ++nf) {
            const int cloc = wc * 64 + nf * 16 + fr;        // local col
            f32x4 a = acc[mf][nf];
            #pragma unroll
            for (int j = 0; j < 4; ++j) {
                const int rloc = rloc0 + j;
                float e = (diag && rloc == cloc) ? 0.f : __expf((a[j] - 1.0f) * INV_T);
                rs[j]      += e;
                colsum[nf] += e;
                if (posblk && rloc == cloc) {
                    const int grow = br * 256 + rloc;
                    pos[grow]        = a[j];
                    pos[grow + 4096] = a[j];
                }
            }
        }
        #pragma unroll
        for (int m = 1; m < 16; m <<= 1) {
            #pragma unroll
            for (int j = 0; j < 4; ++j) rs[j] += __shfl_xor(rs[j], m, 64);
        }
        if (fr == 0) {
            float* p = rowp + (size_t)(br * 256 + rloc0) * 128 + bc * 4 + wc;
            #pragma unroll
            for (int j = 0; j < 4; ++j) p[j * 128] = rs[j];
        }
    }

    if (!diag) {
        #pragma unroll
        for (int m = 16; m < 64; m <<= 1) {
            #pragma unroll
            for (int nf = 0; nf < 4; ++nf) colsum[nf] += __shfl_xor(colsum[nf], m, 64);
        }
        if (kl == 0) {
            #pragma unroll
            for (int nf = 0; nf < 4; ++nf) {
                const int col = bc * 256 + wc * 64 + nf * 16 + fr;
                colp[(size_t)col * 64 + br * 2 + wr] = colsum[nf];
            }
        }
    }
}

// ---------- kernel 3: per-row loss = ln(S) + 1/T - pos/T ----------
__global__ void ntx_loss(const float* __restrict__ rowp, const float* __restrict__ colp,
                         const float* __restrict__ pos, float* __restrict__ loss)
{
    const int w    = threadIdx.x >> 6;
    const int lane = threadIdx.x & 63;
    const int row  = blockIdx.x * 4 + w;
    const int R    = row >> 8;           // 256-row block index

    float s = 0.f;
    float v0 = rowp[(size_t)row * 128 + lane];
    float v1 = rowp[(size_t)row * 128 + 64 + lane];
    float v2 = colp[(size_t)row * 64 + lane];
    if (lane      >= 4 * R) s += v0;
    if (lane + 64 >= 4 * R) s += v1;
    if (lane      <  2 * R) s += v2;

    #pragma unroll
    for (int m = 1; m < 64; m <<= 1) s += __shfl_xor(s, m, 64);

    if (lane == 0)
        loss[row] = __logf(s) + INV_T - pos[row] * INV_T;
}

// ---------- kernel 4: deterministic mean ----------
__global__ void ntx_reduce(const float* __restrict__ loss, float* __restrict__ out)
{
    __shared__ float sm[1024];
    const int t = threadIdx.x;
    float s = 0.f;
    for (int i = t; i < N2; i += 1024) s += loss[i];
    sm[t] = s;
    __syncthreads();
    for (int wdt = 512; wdt > 0; wdt >>= 1) {
        if (t < wdt) sm[t] += sm[t + wdt];
        __syncthreads();
    }
    if (t == 0) out[0] = sm[0] * (1.0f / (float)N2);
}

extern "C" void kernel_launch(void* const* d_in, const int* in_sizes, int n_in,
                              void* d_out, int out_size, void* d_ws, size_t ws_size,
                              hipStream_t stream)
{
    const float* z1 = (const float*)d_in[0];
    const float* z2 = (const float*)d_in[1];
    float* out = (float*)d_out;

    // workspace layout
    u16*   zn   = (u16*)d_ws;                                    // 4 MB
    float* rowp = (float*)((char*)d_ws + (4u << 20));            // 8192*128*4 = 4 MB
    float* colp = (float*)((char*)d_ws + (8u << 20));            // 8192*64*4  = 2 MB
    float* loss = (float*)((char*)d_ws + (10u << 20));           // 32 KB
    float* pos  = loss + N2;                                     // 32 KB

    ntx_norm  <<<N2 / 4, 256, 0, stream>>>(z1, z2, zn);
    ntx_gemm  <<<NTRI, 512, 0, stream>>>(zn, rowp, colp, pos);
    ntx_loss  <<<N2 / 4, 256, 0, stream>>>(rowp, colp, pos, loss);
    ntx_reduce<<<1, 1024, 0, stream>>>(loss, out);
}

// Round 6
// 47.789 us; speedup vs baseline: 4.7747x; 4.7747x over previous
//
#include <hip/hip_runtime.h>

#define N2   8192
#define DDIM 256
#define NBLK 64   // 8192/128 row/col blocks
#define NTRI 2080 // 64*65/2 upper-triangle blocks

static constexpr float INV_T = 1.0f / 0.07f;

using bf16x8 = __attribute__((ext_vector_type(8))) __bf16;
using f32x4  = __attribute__((ext_vector_type(4))) float;
using u16x4  = __attribute__((ext_vector_type(4))) unsigned short;
typedef unsigned short u16;
typedef unsigned int   u32;

#define GL2LDS(gp, lp) __builtin_amdgcn_global_load_lds( \
    (const __attribute__((address_space(1))) void*)(gp), \
    (__attribute__((address_space(3))) void*)(lp), 16, 0, 0)

// ---------- helpers ----------
__device__ __forceinline__ u16 f2bf(float f) {
    u32 u = __float_as_uint(f);
    u32 r = (u + 0x7fffu + ((u >> 16) & 1u)) >> 16;   // RNE
    return (u16)r;
}

// ---------- kernel 1: normalize rows, f32 -> bf16 ----------
__global__ void ntx_norm(const float* __restrict__ z1, const float* __restrict__ z2,
                         u16* __restrict__ zn)
{
    const int w    = threadIdx.x >> 6;
    const int lane = threadIdx.x & 63;
    const int row  = blockIdx.x * 4 + w;

    const float* src = (row < 4096) ? (z1 + (size_t)row * DDIM)
                                    : (z2 + (size_t)(row - 4096) * DDIM);
    float4 v = *(const float4*)(src + lane * 4);
    float ss = v.x * v.x + v.y * v.y + v.z * v.z + v.w * v.w;
    #pragma unroll
    for (int m = 1; m < 64; m <<= 1) ss += __shfl_xor(ss, m, 64);

    float inv = 1.0f / fmaxf(sqrtf(ss), 1e-8f);

    u16x4 o;
    o.x = f2bf(v.x * inv); o.y = f2bf(v.y * inv);
    o.z = f2bf(v.z * inv); o.w = f2bf(v.w * inv);
    *(u16x4*)(zn + (size_t)row * DDIM + lane * 4) = o;
}

// ---------- kernel 2: upper-triangle sim blocks (R2 structure + GL2LDS staging) ----------
// 128x128 tile, 4 waves (2x2), BK=64, single-buffered 32 KB LDS, ~3 blocks/CU.
// global_load_lds width-16: linear LDS dest + inverse-swizzled global source,
// XOR-swizzled ds_read (rule-21 pair, proven R3-R5).
__global__ __launch_bounds__(256, 3)
void ntx_gemm(const u16* __restrict__ zn, float* __restrict__ partials,
              float* __restrict__ pos)
{
    __shared__ u16 lsA[8192];   // 128 rows x 64 bf16 (128 B/row) = 16 KB
    __shared__ u16 lsB[8192];

    const int tid  = threadIdx.x;
    const int lane = tid & 63;
    const int w    = tid >> 6;       // 0..3
    const int wr   = w >> 1;         // 0..1
    const int wc   = w & 1;          // 0..1

    // triangle decode: blockIdx.x -> (br, bc), br <= bc
    const int t = (int)blockIdx.x;
    int br = (int)((129.0f - sqrtf(16641.0f - 8.0f * (float)t)) * 0.5f);
    while ((br + 1) * (129 - (br + 1)) / 2 <= t) ++br;
    while (br * (129 - br) / 2 > t) --br;
    const int bc = br + (t - br * (129 - br) / 2);

    const int fr  = lane & 15;               // fragment row/col
    const int kl  = lane >> 4;               // k-group 0..3
    const int swz = (fr & 7) << 4;           // read-side swizzle

    // staging: issue i covers rows i*32 + w*8 + (lane>>3); wave-uniform LDS base,
    // inverse-swizzled global source column (rule-21 pair with read swizzle)
    const int srow = w * 8 + (lane >> 3);                      // 0..31
    const int scsw = ((lane & 7) * 16) ^ ((lane >> 3) << 4);

    auto stage = [&](int kt) {
        const char* gA = (const char*)zn + (size_t)(br * 128 + srow) * 512 + kt * 128 + scsw;
        const char* gB = (const char*)zn + (size_t)(bc * 128 + srow) * 512 + kt * 128 + scsw;
        u16* lA = &lsA[w * 512];            // (w*8 rows) * 64 u16/row
        u16* lB = &lsB[w * 512];
        #pragma unroll
        for (int i = 0; i < 4; ++i) {       // +32 rows per issue = 16384 B global, 2048 u16 LDS
            GL2LDS(gA + (size_t)i * 16384, lA + i * 2048);
            GL2LDS(gB + (size_t)i * 16384, lB + i * 2048);
        }
    };

    f32x4 acc[4][4] = {};

    stage(0);
    __syncthreads();                 // vmcnt+lgkm drained: tile visible

    #pragma unroll
    for (int kt = 0; kt < 4; ++kt) {
        #pragma unroll
        for (int ks = 0; ks < 2; ++ks) {
            const int kb = ks * 64 + kl * 16;
            bf16x8 af[4], bv[4];
            #pragma unroll
            for (int mf = 0; mf < 4; ++mf) {
                const int r = wr * 64 + mf * 16 + fr;
                af[mf] = *(const bf16x8*)((const char*)lsA + r * 128 + (kb ^ swz));
            }
            #pragma unroll
            for (int nf = 0; nf < 4; ++nf) {
                const int c = wc * 64 + nf * 16 + fr;
                bv[nf] = *(const bf16x8*)((const char*)lsB + c * 128 + (kb ^ swz));
            }
            #pragma unroll
            for (int mf = 0; mf < 4; ++mf)
                #pragma unroll
                for (int nf = 0; nf < 4; ++nf)
                    acc[mf][nf] = __builtin_amdgcn_mfma_f32_16x16x32_bf16(
                        af[mf], bv[nf], acc[mf][nf], 0, 0, 0);
        }
        if (kt < 3) {
            __syncthreads();         // all waves done reading LDS
            stage(kt + 1);
            __syncthreads();         // staged data visible
        }
    }

    // ---- epilogue (R2-proven) ----
    // e = exp((dot-1)/T), diag masked. Row sums -> partials[row][2*bc+wc];
    // off-diag blocks add transpose col sums -> partials[col][2*br+wr].
    const bool offdiag = (br != bc);
    const bool posblk  = (bc == br + 32);
    float colsum[4] = {0.f, 0.f, 0.f, 0.f};

    #pragma unroll
    for (int mf = 0; mf < 4; ++mf) {
        float rs[4] = {0.f, 0.f, 0.f, 0.f};
        const int rowq = br * 128 + wr * 64 + mf * 16 + kl * 4;
        #pragma unroll
        for (int nf = 0; nf < 4; ++nf) {
            const int col = bc * 128 + wc * 64 + nf * 16 + fr;
            f32x4 a = acc[mf][nf];
            #pragma unroll
            for (int j = 0; j < 4; ++j) {
                float e = (rowq + j == col) ? 0.f : __expf((a[j] - 1.0f) * INV_T);
                rs[j]      += e;
                colsum[nf] += e;
                if (posblk && (rowq + j + 4096 == col)) {
                    pos[rowq + j] = a[j];
                    pos[col]      = a[j];
                }
            }
        }
        #pragma unroll
        for (int m = 1; m < 16; m <<= 1) {
            #pragma unroll
            for (int j = 0; j < 4; ++j) rs[j] += __shfl_xor(rs[j], m, 64);
        }
        if (fr == 0) {
            float* p = partials + (size_t)rowq * 128 + bc * 2 + wc;
            p[0]   = rs[0];
            p[128] = rs[1];
            p[256] = rs[2];
            p[384] = rs[3];
        }
    }

    if (offdiag) {
        #pragma unroll
        for (int m = 16; m < 64; m <<= 1) {
            #pragma unroll
            for (int nf = 0; nf < 4; ++nf) colsum[nf] += __shfl_xor(colsum[nf], m, 64);
        }
        if (kl == 0) {
            #pragma unroll
            for (int nf = 0; nf < 4; ++nf) {
                const int col = bc * 128 + wc * 64 + nf * 16 + fr;
                partials[(size_t)col * 128 + br * 2 + wr] = colsum[nf];
            }
        }
    }
}

// ---------- kernel 3: per-row loss = ln(S) + 1/T - pos/T ----------
__global__ void ntx_loss(const float* __restrict__ partials, const float* __restrict__ pos,
                         float* __restrict__ loss)
{
    const int w    = threadIdx.x >> 6;
    const int lane = threadIdx.x & 63;
    const int row  = blockIdx.x * 4 + w;

    float S = partials[(size_t)row * 128 + lane] + partials[(size_t)row * 128 + 64 + lane];
    #pragma unroll
    for (int m = 1; m < 64; m <<= 1) S += __shfl_xor(S, m, 64);

    if (lane == 0)
        loss[row] = __logf(S) + INV_T - pos[row] * INV_T;
}

// ---------- kernel 4: deterministic mean ----------
__global__ void ntx_reduce(const float* __restrict__ loss, float* __restrict__ out)
{
    __shared__ float sm[1024];
    const int t = threadIdx.x;
    float s = 0.f;
    for (int i = t; i < N2; i += 1024) s += loss[i];
    sm[t] = s;
    __syncthreads();
    for (int wdt = 512; wdt > 0; wdt >>= 1) {
        if (t < wdt) sm[t] += sm[t + wdt];
        __syncthreads();
    }
    if (t == 0) out[0] = sm[0] * (1.0f / (float)N2);
}

extern "C" void kernel_launch(void* const* d_in, const int* in_sizes, int n_in,
                              void* d_out, int out_size, void* d_ws, size_t ws_size,
                              hipStream_t stream)
{
    const float* z1 = (const float*)d_in[0];
    const float* z2 = (const float*)d_in[1];
    float* out = (float*)d_out;

    // workspace layout
    u16*   zn       = (u16*)d_ws;                                   // 4 MB
    float* partials = (float*)((char*)d_ws + (4u << 20));           // 8192*128*4 = 4 MB
    float* loss     = (float*)((char*)d_ws + (8u << 20));           // 32 KB
    float* pos      = loss + N2;                                    // 32 KB

    ntx_norm  <<<N2 / 4, 256, 0, stream>>>(z1, z2, zn);
    ntx_gemm  <<<NTRI, 256, 0, stream>>>(zn, partials, pos);
    ntx_loss  <<<N2 / 4, 256, 0, stream>>>(partials, pos, loss);
    ntx_reduce<<<1, 1024, 0, stream>>>(loss, out);
}